// Round 5
// baseline (52.204 us; speedup 1.0000x reference)
//
#include <hip/hip_runtime.h>
#include <math.h>

#define NN   8
#define INCH 32
#define INN  50000
#define OUTC 64
#define OUTN 8192
#define DD   32
#define CC   256   // NN*INCH

typedef unsigned short ushortT;

__device__ __forceinline__ ushortT f2bf(float f) {
  unsigned u = __float_as_uint(f);
  unsigned r = (u + 0x7FFFu + ((u >> 16) & 1u)) >> 16;   // round-nearest-even
  return (ushortT)r;
}
__device__ __forceinline__ float bf2f(ushortT b) {
  return __uint_as_float(((unsigned)b) << 16);
}

// yT permutation: ushort slot p of row j  <->  c = ((p&7)<<5) | (p>>3).
// So a lane reading 8 contiguous slots [8*l32 .. 8*l32+7] gets c = 32*e + l32, e=0..7.

// Kernel 1: yT[j][p] bf16 (permuted). Reads: 8 lanes per row -> 128B contiguous segments.
__global__ __launch_bounds__(256) void prep_kernel(
    const float* __restrict__ x, const float* __restrict__ nf, ushortT* __restrict__ yT) {
  __shared__ float tile[CC][33];   // stride 33 words: <=2-way banks in all phases
  const int t = threadIdx.x;
  const int j0 = blockIdx.x * 32;
  const int jmax = min(32, INN - j0);   // 50000 = 1562*32 + 16 -> last block 16

  const int q  = t & 7;    // j-quad within window
  const int r0 = t >> 3;   // row within 32-row group

  if (q * 4 < jmax) {
    // nf row = c & 31 = r0 for every pass -> loop-invariant
    const float4 nv = *(const float4*)(nf + (size_t)r0 * INN + j0 + 4 * q);
    #pragma unroll
    for (int p = 0; p < 8; ++p) {
      const int c = (p << 5) + r0;
      const float4 xv = *(const float4*)(x + (size_t)c * INN + j0 + 4 * q);
      float4 pr;
      pr.x = xv.x * nv.x; pr.y = xv.y * nv.y; pr.z = xv.z * nv.z; pr.w = xv.w * nv.w;
      *(float4*)&tile[c][4 * q] = pr;   // bank (r0+4q)%32 -> <=2-way
    }
  }
  __syncthreads();

  // store: lane writes slots 4*lane..4*lane+3 of row jl (512B/row per wave-instr)
  const int lane = t & 63;
  const int wave = t >> 6;
  const int chi = (lane & 1) * 4;   // (p&7) base for slot 4*lane+k, k<4
  const int clo = lane >> 1;        // p>>3
  #pragma unroll
  for (int r = 0; r < 8; ++r) {
    const int jl = wave * 8 + r;
    if (jl < jmax) {
      ushort4 pk;
      pk.x = f2bf(tile[(chi + 0) * 32 + clo][jl]);   // bank (clo+jl)%32 -> 2-way (free)
      pk.y = f2bf(tile[(chi + 1) * 32 + clo][jl]);
      pk.z = f2bf(tile[(chi + 2) * 32 + clo][jl]);
      pk.w = f2bf(tile[(chi + 3) * 32 + clo][jl]);
      ((ushort4*)(yT + (size_t)(j0 + jl) * CC))[lane] = pk;
    }
  }
}

// Kernel 2: 2 o's per wave (lanes 0-31 -> o, lanes 32-63 -> o+1), uint4 = 16B/lane,
// one instruction gathers two full 512B rows. red16 written in NATURAL [o][c] layout.
__global__ __launch_bounds__(256) void gather_kernel(
    const ushortT* __restrict__ yT, const int* __restrict__ A, ushortT* __restrict__ red16) {
  const int t = threadIdx.x;
  const int lane = t & 63;
  const int wave = t >> 6;
  const int opair = blockIdx.x * 8 + wave * 2;
  const int half = lane >> 5;
  const int l32  = lane & 31;
  const int o = opair + half;

  const int4* Aa = (const int4*)(A + (size_t)opair * DD);
  const int4* Ab = (const int4*)(A + (size_t)(opair + 1) * DD);

  float m[8];
  #pragma unroll
  for (int e = 0; e < 8; ++e) m[e] = -INFINITY;

  const ushortT* base = yT + (size_t)l32 * 8;
  #pragma unroll
  for (int g = 0; g < 8; ++g) {
    const int4 va = Aa[g];
    const int4 vb = Ab[g];
    const int ia[4] = {va.x, va.y, va.z, va.w};
    const int ib[4] = {vb.x, vb.y, vb.z, vb.w};
    #pragma unroll
    for (int e = 0; e < 4; ++e) {
      const int idx = half ? ib[e] : ia[e];
      const uint4 v = *(const uint4*)(base + (size_t)idx * CC);
      // dword w: lo16 -> c = 32*(2w)+l32, hi16 -> c = 32*(2w+1)+l32
      m[0] = fmaxf(m[0], __uint_as_float(v.x << 16));
      m[1] = fmaxf(m[1], __uint_as_float(v.x & 0xffff0000u));
      m[2] = fmaxf(m[2], __uint_as_float(v.y << 16));
      m[3] = fmaxf(m[3], __uint_as_float(v.y & 0xffff0000u));
      m[4] = fmaxf(m[4], __uint_as_float(v.z << 16));
      m[5] = fmaxf(m[5], __uint_as_float(v.z & 0xffff0000u));
      m[6] = fmaxf(m[6], __uint_as_float(v.w << 16));
      m[7] = fmaxf(m[7], __uint_as_float(v.w & 0xffff0000u));
    }
  }
  // f2bf is EXACT here (max of bf16-representable values). 64B contiguous per segment.
  ushortT* ro = red16 + (size_t)o * CC + l32;
  #pragma unroll
  for (int e = 0; e < 8; ++e) ro[32 * e] = f2bf(m[e]);
}

// Kernel 3: out[n,k,o] = sum_i red[o][n*32+i]*ft[i][k] + bias[k][o]
// block: n-pair (np) x 64-o tile; wave: (n parity, k-half); lane = o_local
__global__ __launch_bounds__(256) void out_kernel(
    const ushortT* __restrict__ red16, const float* __restrict__ ft,
    const float* __restrict__ bias, float* __restrict__ out) {
  __shared__ float rtile[64][65];   // [o_local][c_local], pad 65 -> <=2-way on all phases
  __shared__ float ftl[32][64];
  const int t = threadIdx.x;
  const int lane = t & 63;
  const int wave = t >> 6;
  const int np = blockIdx.x >> 7;   // 0..3
  const int ot = blockIdx.x & 127;  // 0..127
  const int o0 = ot * 64;
  const int c0 = np * 64;

  // ft -> LDS (2048 floats, coalesced)
  #pragma unroll
  for (int q = 0; q < 8; ++q) {
    const int idx = q * 256 + t;
    ftl[idx >> 6][idx & 63] = ft[idx];
  }
  // red16 tile -> LDS: thread covers 16 c's (32B) of a row; per wave: 8 rows x 128B contiguous
  #pragma unroll
  for (int i = 0; i < 2; ++i) {
    const int r = (t >> 3) + 32 * i;
    const int g = t & 7;
    const ushort4* src = (const ushort4*)(red16 + (size_t)(o0 + r) * CC + c0 + g * 8);
    const ushort4 v0 = src[0];
    const ushort4 v1 = src[1];
    float* dst = &rtile[r][g * 8];
    dst[0] = bf2f(v0.x); dst[1] = bf2f(v0.y); dst[2] = bf2f(v0.z); dst[3] = bf2f(v0.w);
    dst[4] = bf2f(v1.x); dst[5] = bf2f(v1.y); dst[6] = bf2f(v1.z); dst[7] = bf2f(v1.w);
  }
  __syncthreads();

  const int n  = np * 2 + (wave & 1);
  const int kh = (wave >> 1) * 32;
  const int cb = (wave & 1) * 32;

  float rv[32];
  #pragma unroll
  for (int i = 0; i < 32; ++i) rv[i] = rtile[lane][cb + i];   // (lane+cb+i)%32 -> 2-way

  float acc[32];
  #pragma unroll
  for (int kk = 0; kk < 32; ++kk) acc[kk] = 0.f;
  #pragma unroll
  for (int i = 0; i < 32; ++i) {
    #pragma unroll
    for (int kk = 0; kk < 32; ++kk)
      acc[kk] += rv[i] * ftl[i][kh + kk];   // ftl: uniform addr -> broadcast
  }

  float* op = out + (size_t)n * OUTC * OUTN + o0 + lane;
  const float* bp = bias + o0 + lane;
  #pragma unroll
  for (int kk = 0; kk < 32; ++kk) {
    const int k = kh + kk;
    op[(size_t)k * OUTN] = acc[kk] + bp[(size_t)k * OUTN];   // 256B-contiguous stores
  }
}

extern "C" void kernel_launch(void* const* d_in, const int* in_sizes, int n_in,
                              void* d_out, int out_size, void* d_ws, size_t ws_size,
                              hipStream_t stream) {
  const float* x    = (const float*)d_in[0];
  const float* nf   = (const float*)d_in[1];
  const float* ft   = (const float*)d_in[2];
  const float* bias = (const float*)d_in[3];
  const int*   A    = (const int*)d_in[4];
  float* out = (float*)d_out;

  ushortT* yT    = (ushortT*)d_ws;                                 // 50000*256*2 = 25.6 MB
  ushortT* red16 = (ushortT*)((char*)d_ws + (size_t)INN * CC * 2); // 8192*256*2  =  4.2 MB

  hipLaunchKernelGGL(prep_kernel,   dim3((INN + 31) / 32), dim3(256), 0, stream, x, nf, yT);
  hipLaunchKernelGGL(gather_kernel, dim3(OUTN / 8),        dim3(256), 0, stream, yT, A, red16);
  hipLaunchKernelGGL(out_kernel,    dim3(512),             dim3(256), 0, stream, red16, ft, bias, out);
}